// Round 14
// baseline (307.406 us; speedup 1.0000x reference)
//
#include <hip/hip_runtime.h>

#define HW 16384
#define CIN 512
#define PL 256
#define EPSF 1e-5f
#define SLO 0.0009765625f   // 2^-10

using half8  = __attribute__((ext_vector_type(8))) _Float16;
using half4v = __attribute__((ext_vector_type(4))) _Float16;
using f32x4  = __attribute__((ext_vector_type(4))) float;

__device__ inline void gload_lds16(const void* g, void* l) {
  __builtin_amdgcn_global_load_lds((const __attribute__((address_space(1))) void*)g,
                                   (__attribute__((address_space(3))) void*)l, 16, 0, 0);
}

// ---------- kernel 0a: stream x -> Xh/Xl (row-major fp16 hi/lo) + xsum
__global__ __launch_bounds__(256) void k_conv(const float* __restrict__ x,
                                              _Float16* __restrict__ Xh,
                                              _Float16* __restrict__ Xl,
                                              float* __restrict__ xsum) {
  __shared__ float ws4[4];
  int row = blockIdx.x;                // b*512 + c
  int tid = threadIdx.x;
  const float* xr = x + ((size_t)row << 14);
  _Float16* hr = Xh + ((size_t)row << 14);
  _Float16* lr = Xl + ((size_t)row << 14);
  float s = 0.f;
#pragma unroll
  for (int j = 0; j < 8; ++j) {
    int o = j * 2048 + tid * 8;
    float4 v0 = *reinterpret_cast<const float4*>(xr + o);
    float4 v1 = *reinterpret_cast<const float4*>(xr + o + 4);
    half8 h, l;
    h[0] = (_Float16)v0.x; h[1] = (_Float16)v0.y; h[2] = (_Float16)v0.z; h[3] = (_Float16)v0.w;
    h[4] = (_Float16)v1.x; h[5] = (_Float16)v1.y; h[6] = (_Float16)v1.z; h[7] = (_Float16)v1.w;
    l[0] = (_Float16)((v0.x - (float)h[0]) * 1024.f);
    l[1] = (_Float16)((v0.y - (float)h[1]) * 1024.f);
    l[2] = (_Float16)((v0.z - (float)h[2]) * 1024.f);
    l[3] = (_Float16)((v0.w - (float)h[3]) * 1024.f);
    l[4] = (_Float16)((v1.x - (float)h[4]) * 1024.f);
    l[5] = (_Float16)((v1.y - (float)h[5]) * 1024.f);
    l[6] = (_Float16)((v1.z - (float)h[6]) * 1024.f);
    l[7] = (_Float16)((v1.w - (float)h[7]) * 1024.f);
    *reinterpret_cast<half8*>(hr + o) = h;
    *reinterpret_cast<half8*>(lr + o) = l;
    s += v0.x + v0.y + v0.z + v0.w + v1.x + v1.y + v1.z + v1.w;
  }
#pragma unroll
  for (int m = 1; m < 64; m <<= 1) s += __shfl_xor(s, m);
  if ((tid & 63) == 0) ws4[tid >> 6] = s;
  __syncthreads();
  if (tid == 0) xsum[row] = ws4[0] + ws4[1] + ws4[2] + ws4[3];
}

// ---------- kernel 0b: fp16 transpose Xh [b][c][hw] -> xT [b][hw][c]
__global__ __launch_bounds__(256) void k_xp16(const _Float16* __restrict__ Xh,
                                              _Float16* __restrict__ xT) {
  __shared__ _Float16 lds[64 * 72];
  int hw0 = blockIdx.x << 6;
  int c0 = blockIdx.y << 6;
  int b = blockIdx.z;
  int tid = threadIdx.x;
  int rl = tid >> 3, seg = tid & 7;
  const _Float16* hb = Xh + ((size_t)b << 23);
#pragma unroll
  for (int pass = 0; pass < 2; ++pass) {
    int cl = pass * 32 + rl;
    half8 v = *reinterpret_cast<const half8*>(hb + ((size_t)(c0 + cl) << 14) + hw0 + seg * 8);
#pragma unroll
    for (int e = 0; e < 8; ++e) lds[(seg * 8 + e) * 72 + cl] = v[e];
  }
  __syncthreads();
  _Float16* tb = xT + (((size_t)b << 14) + hw0) * CIN + c0;
#pragma unroll
  for (int pass = 0; pass < 2; ++pass) {
    int hwl = pass * 32 + rl;
    half8 o = *reinterpret_cast<const half8*>(&lds[hwl * 72 + seg * 8]);
    *reinterpret_cast<half8*>(tb + (size_t)hwl * CIN + seg * 8) = o;
  }
}

// ---------- kernel 1: Gram, BK=64, double-buffered LDS, ONE barrier per K-step.
// u<10: GH = Xh.Xh^T upper 128-tiles (mirrored in k_sym); u>=10: C1 = Xl.Xh^T all 16 tiles.
__global__ __launch_bounds__(256, 2) void k_gram(const _Float16* __restrict__ Xh,
                                                 const _Float16* __restrict__ Xl,
                                                 float* __restrict__ GH,
                                                 float* __restrict__ C1) {
  __shared__ _Float16 lds[2][2][128 * 64];   // [buf][A/B], 16KB each = 64KB
  int wg = blockIdx.x;                 // 1664 blocks
  int id = (wg & 7) * 208 + (wg >> 3); // XCD-chunked (bijective: 1664 % 8 == 0)
  int b = id / 416;
  int rem = id % 416;
  int ks = rem / 26;                   // 0..15, K-chunk = 1024
  int u = rem % 26;
  int chain, ti, tj;
  if (u < 10) {
    chain = 0;
    ti = 0;
    while ((ti + 1) * (ti + 2) / 2 <= u) ++ti;
    tj = u - ti * (ti + 1) / 2;        // ti >= tj
  } else {
    chain = 1;
    int t = u - 10;
    ti = t >> 2; tj = t & 3;
  }
  int tid = threadIdx.x;
  int wave = tid >> 6, lane = tid & 63, l15 = lane & 15, l4 = lane >> 4;
  int wr = wave >> 1, wc = wave & 1;
  const _Float16* Asrc = (chain ? Xl : Xh) + (size_t)b * CIN * HW;
  const _Float16* Bsrc = Xh + (size_t)b * CIN * HW;
  float* D = chain ? C1 : GH;

  int srow = lane >> 3;
  int sgran = (lane & 7) ^ (srow & 7);
  int kbase = ks << 10;                // chunk of 1024 elements, 16 steps of 64
  const _Float16* gA[4];
  const _Float16* gB[4];
#pragma unroll
  for (int i = 0; i < 4; ++i) {
    int row = i * 32 + wave * 8 + srow;
    gA[i] = Asrc + (size_t)(ti * 128 + row) * HW + kbase + sgran * 8;
    gB[i] = Bsrc + (size_t)(tj * 128 + row) * HW + kbase + sgran * 8;
  }

  int adA[4][2], adB[4][2];
#pragma unroll
  for (int rf = 0; rf < 4; ++rf) {
    int r = wr * 64 + rf * 16 + l15;
#pragma unroll
    for (int ksub = 0; ksub < 2; ++ksub)
      adA[rf][ksub] = r * 128 + (((ksub * 4 + l4) ^ (r & 7)) << 4);
  }
#pragma unroll
  for (int cf = 0; cf < 4; ++cf) {
    int c = wc * 64 + cf * 16 + l15;
#pragma unroll
    for (int ksub = 0; ksub < 2; ++ksub)
      adB[cf][ksub] = c * 128 + (((ksub * 4 + l4) ^ (c & 7)) << 4);
  }

  f32x4 acc[4][4];
#pragma unroll
  for (int rf = 0; rf < 4; ++rf)
#pragma unroll
    for (int cf = 0; cf < 4; ++cf) acc[rf][cf] = f32x4{0.f, 0.f, 0.f, 0.f};

  // prologue: stage step 0 into buf 0
  {
    char* dA = (char*)lds[0][0] + wave * 1024;
    char* dB = (char*)lds[0][1] + wave * 1024;
#pragma unroll
    for (int i = 0; i < 4; ++i) {
      gload_lds16(gA[i], dA + i * 4096);
      gload_lds16(gB[i], dB + i * 4096);
    }
  }
  __syncthreads();

  for (int s = 0; s < 16; ++s) {
    // stage next step into the other buffer (overlaps with compute below)
    if (s + 1 < 16) {
      int ko = (s + 1) * 64;
      char* dA = (char*)lds[(s + 1) & 1][0] + wave * 1024;
      char* dB = (char*)lds[(s + 1) & 1][1] + wave * 1024;
#pragma unroll
      for (int i = 0; i < 4; ++i) {
        gload_lds16(gA[i] + ko, dA + i * 4096);
        gload_lds16(gB[i] + ko, dB + i * 4096);
      }
    }
    // compute current buffer
    char* cA = (char*)lds[s & 1][0];
    char* cB = (char*)lds[s & 1][1];
#pragma unroll
    for (int ksub = 0; ksub < 2; ++ksub) {
      half8 af[4], bf[4];
#pragma unroll
      for (int rf = 0; rf < 4; ++rf)
        af[rf] = *reinterpret_cast<const half8*>(cA + adA[rf][ksub]);
#pragma unroll
      for (int cf = 0; cf < 4; ++cf)
        bf[cf] = *reinterpret_cast<const half8*>(cB + adB[cf][ksub]);
#pragma unroll
      for (int rf = 0; rf < 4; ++rf)
#pragma unroll
        for (int cf = 0; cf < 4; ++cf)
          acc[rf][cf] = __builtin_amdgcn_mfma_f32_16x16x32_f16(af[rf], bf[cf], acc[rf][cf], 0, 0, 0);
    }
    __syncthreads();   // drains this step's reads AND next step's staged loads
  }

  size_t bo = (size_t)b << 18;
#pragma unroll
  for (int rf = 0; rf < 4; ++rf)
#pragma unroll
    for (int cf = 0; cf < 4; ++cf)
#pragma unroll
      for (int r = 0; r < 4; ++r) {
        int i = ti * 128 + wr * 64 + rf * 16 + l4 * 4 + r;
        int j = tj * 128 + wc * 64 + cf * 16 + l15;
        atomicAdd(D + bo + ((size_t)i << 9) + j, acc[rf][cf][r]);
      }
}

// ---------- kernel 2: Gs[i][j] = GHs[i][j] + SLO*(C1[i][j] + C1[j][i]);
__global__ __launch_bounds__(256) void k_sym(const float* __restrict__ GH,
                                             const float* __restrict__ C1,
                                             float* __restrict__ Gs) {
  __shared__ float T1[64 * 65];
  __shared__ float TG[64 * 65];
  int I = blockIdx.x, J = blockIdx.y, b = blockIdx.z;
  int i0 = I << 6, j0 = J << 6;
  bool upper = (I >> 1) >= (J >> 1);
  size_t bo = (size_t)b << 18;
  int tid = threadIdx.x;
  int r = tid >> 2, cs = (tid & 3) << 4;
#pragma unroll
  for (int u = 0; u < 16; u += 4) {
    size_t toff = bo + (((size_t)(j0 + r)) << 9) + i0 + cs + u;
    float4 v = *reinterpret_cast<const float4*>(C1 + toff);
    T1[r * 65 + cs + u + 0] = v.x; T1[r * 65 + cs + u + 1] = v.y;
    T1[r * 65 + cs + u + 2] = v.z; T1[r * 65 + cs + u + 3] = v.w;
    if (!upper) {
      float4 g = *reinterpret_cast<const float4*>(GH + toff);
      TG[r * 65 + cs + u + 0] = g.x; TG[r * 65 + cs + u + 1] = g.y;
      TG[r * 65 + cs + u + 2] = g.z; TG[r * 65 + cs + u + 3] = g.w;
    }
  }
  __syncthreads();
#pragma unroll
  for (int u = 0; u < 16; u += 4) {
    size_t off = bo + (((size_t)(i0 + r)) << 9) + j0 + cs + u;
    float4 c = *reinterpret_cast<const float4*>(C1 + off);
    float t0 = T1[(cs + u + 0) * 65 + r];
    float t1 = T1[(cs + u + 1) * 65 + r];
    float t2 = T1[(cs + u + 2) * 65 + r];
    float t3 = T1[(cs + u + 3) * 65 + r];
    float4 o;
    if (upper) {
      float4 h = *reinterpret_cast<const float4*>(GH + off);
      o.x = h.x + SLO * (c.x + t0);
      o.y = h.y + SLO * (c.y + t1);
      o.z = h.z + SLO * (c.z + t2);
      o.w = h.w + SLO * (c.w + t3);
    } else {
      o.x = TG[(cs + u + 0) * 65 + r] + SLO * (c.x + t0);
      o.y = TG[(cs + u + 1) * 65 + r] + SLO * (c.y + t1);
      o.z = TG[(cs + u + 2) * 65 + r] + SLO * (c.z + t2);
      o.w = TG[(cs + u + 3) * 65 + r] + SLO * (c.w + t3);
    }
    *reinterpret_cast<float4*>(Gs + off) = o;
  }
}

// ---------- kernel 3: V[b][ocol][i] = sum_j W[ocol][j] * Gs[b][i][j]
__global__ __launch_bounds__(256) void k_V(const float* __restrict__ Gs,
                                           const float* __restrict__ Wg,
                                           const float* __restrict__ Wt,
                                           float* __restrict__ V) {
  __shared__ float Gl[64 * 65];
  __shared__ float Wl[64 * 65];
  int it = blockIdx.x, ot = blockIdx.y, b = blockIdx.z;
  int i0 = it << 6, o0 = ot << 6;
  int tid = threadIdx.x;
  int srow = tid >> 2, sseg = (tid & 3) << 4;
  const float* gsb = Gs + ((size_t)b << 18);
  int orow = o0 + srow;
  const float* wrow = (orow < 256) ? (Wg + (size_t)orow * 512) : (Wt + (size_t)(orow - 256) * 512);
  float acc[4][4];
#pragma unroll
  for (int a = 0; a < 4; ++a)
#pragma unroll
    for (int c = 0; c < 4; ++c) acc[a][c] = 0.f;
  int oy = (tid >> 4) << 2, ix = (tid & 15) << 2;
  for (int jc = 0; jc < 512; jc += 64) {
    __syncthreads();
#pragma unroll
    for (int u = 0; u < 16; u += 4) {
      float4 g = *reinterpret_cast<const float4*>(gsb + ((size_t)(i0 + srow) << 9) + jc + sseg + u);
      float4 w = *reinterpret_cast<const float4*>(wrow + jc + sseg + u);
      Gl[srow * 65 + sseg + u + 0] = g.x; Gl[srow * 65 + sseg + u + 1] = g.y;
      Gl[srow * 65 + sseg + u + 2] = g.z; Gl[srow * 65 + sseg + u + 3] = g.w;
      Wl[srow * 65 + sseg + u + 0] = w.x; Wl[srow * 65 + sseg + u + 1] = w.y;
      Wl[srow * 65 + sseg + u + 2] = w.z; Wl[srow * 65 + sseg + u + 3] = w.w;
    }
    __syncthreads();
    for (int j = 0; j < 64; ++j) {
      float w0 = Wl[(oy + 0) * 65 + j], w1 = Wl[(oy + 1) * 65 + j];
      float w2 = Wl[(oy + 2) * 65 + j], w3 = Wl[(oy + 3) * 65 + j];
      float g0 = Gl[(ix + 0) * 65 + j], g1 = Gl[(ix + 1) * 65 + j];
      float g2 = Gl[(ix + 2) * 65 + j], g3 = Gl[(ix + 3) * 65 + j];
      acc[0][0] += w0 * g0; acc[0][1] += w0 * g1; acc[0][2] += w0 * g2; acc[0][3] += w0 * g3;
      acc[1][0] += w1 * g0; acc[1][1] += w1 * g1; acc[1][2] += w1 * g2; acc[1][3] += w1 * g3;
      acc[2][0] += w2 * g0; acc[2][1] += w2 * g1; acc[2][2] += w2 * g2; acc[2][3] += w2 * g3;
      acc[3][0] += w3 * g0; acc[3][1] += w3 * g1; acc[3][2] += w3 * g2; acc[3][3] += w3 * g3;
    }
  }
  float* vb = V + ((size_t)b << 18);
#pragma unroll
  for (int a = 0; a < 4; ++a) {
    float4 vv = {acc[a][0], acc[a][1], acc[a][2], acc[a][3]};
    *reinterpret_cast<float4*>(vb + ((size_t)(o0 + oy + a) << 9) + i0 + ix) = vv;
  }
}

// ---------- kernel 4: att/tsq/tsum per (b,o)
__global__ __launch_bounds__(256) void k_red2(const float* __restrict__ V,
                                              const float* __restrict__ xsum,
                                              const float* __restrict__ Wp,
                                              const float* __restrict__ Wt,
                                              float* __restrict__ att,
                                              float* __restrict__ tsum,
                                              float* __restrict__ tsq) {
  int blk = blockIdx.x;
  int b = blk >> 4;
  int og = (blk & 15) << 4;
  int tid = threadIdx.x;
  int ol = tid >> 4, seg = tid & 15;
  int o = og + ol;
  const float* vg = V + ((size_t)b << 18) + ((size_t)o << 9) + seg * 32;
  const float* vt = V + ((size_t)b << 18) + ((size_t)(256 + o) << 9) + seg * 32;
  const float* wp = Wp + (size_t)o * 512 + seg * 32;
  const float* wt = Wt + (size_t)o * 512 + seg * 32;
  const float* xs = xsum + b * CIN + seg * 32;
  float sa = 0.f, sq = 0.f, sm = 0.f;
#pragma unroll
  for (int i = 0; i < 32; i += 4) {
    float4 a = *reinterpret_cast<const float4*>(vg + i);
    float4 p = *reinterpret_cast<const float4*>(wp + i);
    float4 c = *reinterpret_cast<const float4*>(vt + i);
    float4 t = *reinterpret_cast<const float4*>(wt + i);
    float4 s = *reinterpret_cast<const float4*>(xs + i);
    sa += a.x * p.x + a.y * p.y + a.z * p.z + a.w * p.w;
    sq += c.x * t.x + c.y * t.y + c.z * t.z + c.w * t.w;
    sm += t.x * s.x + t.y * s.y + t.z * s.z + t.w * s.w;
  }
#pragma unroll
  for (int m = 1; m < 16; m <<= 1) {
    sa += __shfl_xor(sa, m);
    sq += __shfl_xor(sq, m);
    sm += __shfl_xor(sm, m);
  }
  if (seg == 0) {
    att[b * PL + o] = sa;
    tsq[b * PL + o] = sq;
    tsum[b * PL + o] = sm;
  }
}

// ---------- kernel 5: graph math (one block, 1024 threads)
__global__ __launch_bounds__(1024) void k_graph(
    const float* __restrict__ att, const float* __restrict__ tsum, const float* __restrict__ tsq,
    const float* __restrict__ W_adj, const float* __restrict__ bnag, const float* __restrict__ bnab,
    const float* __restrict__ bnam, const float* __restrict__ bnav,
    const float* __restrict__ W_wg, const float* __restrict__ bwgg, const float* __restrict__ bwgb,
    const float* __restrict__ bwgm, const float* __restrict__ bwgv,
    const float* __restrict__ Wz, const float* __restrict__ gng, const float* __restrict__ gnb,
    float* __restrict__ sA, float* __restrict__ sB) {
  __shared__ float att_l[4 * 256];
  __shared__ float z_l[4 * 256];
  __shared__ float zv_l[4 * 256];
  int tid = threadIdx.x;
  att_l[tid] = att[tid];
  __syncthreads();
  int b = tid >> 8, r = tid & 255, i = r >> 3, k = r & 7;
  float z1 = 0.f;
#pragma unroll
  for (int m = 0; m < 32; ++m) z1 += W_adj[i * 32 + m] * att_l[b * 256 + k * 32 + m];
  float inv = rsqrtf(bnav[i] + EPSF);
  float z = (z1 - bnam[i]) * inv * bnag[i] + bnab[i];
  z = fmaxf(z, 0.f) + att_l[b * 256 + k * 32 + i];
  z_l[b * 256 + i * 8 + k] = z;
  __syncthreads();
  float z2 = 0.f;
#pragma unroll
  for (int e = 0; e < 8; ++e) z2 += W_wg[k * 8 + e] * z_l[b * 256 + i * 8 + e];
  float inv2 = rsqrtf(bwgv[k] + EPSF);
  z2 = (z2 - bwgm[k]) * inv2 * bwgg[k] + bwgb[k];
  zv_l[b * 256 + i * 8 + k] = fmaxf(z2, 0.f);
  __syncthreads();
  int g = r;
  float s = zv_l[b * 256 + g];
  float m1 = tsum[b * 256 + g] * (1.f / 16384.f);
  float m2 = tsq[b * 256 + g] * (1.f / 16384.f);
  float a0 = Wz[2 * g] * s, a1 = Wz[2 * g + 1] * s;
  float mu = 0.5f * (a0 + a1) * m1;
  float ey2 = 0.5f * (a0 * a0 + a1 * a1) * m2;
  float var = ey2 - mu * mu;
  float invg = rsqrtf(var + EPSF);
  int c = b * CIN + 2 * g;
  sA[c]     = a0 * invg * gng[2 * g];
  sA[c + 1] = a1 * invg * gng[2 * g + 1];
  sB[c]     = gnb[2 * g]     - mu * invg * gng[2 * g];
  sB[c + 1] = gnb[2 * g + 1] - mu * invg * gng[2 * g + 1];
}

// ---------- kernel 6: M[b][c][k] = fp16(sA[b,c]*Wt[c>>1][k] + (c==k))
__global__ __launch_bounds__(256) void k_M(const float* __restrict__ Wt,
                                           const float* __restrict__ sA,
                                           _Float16* __restrict__ M) {
  int idx = blockIdx.x * 256 + threadIdx.x;
  int k8 = idx & 63;
  int c = (idx >> 6) & 511;
  int b = idx >> 15;
  float s = sA[b * 512 + c];
  const float* wrow = Wt + ((size_t)(c >> 1) << 9) + k8 * 8;
  int kbase = k8 * 8;
  half8 h;
#pragma unroll
  for (int j = 0; j < 8; ++j) {
    float v = s * wrow[j] + ((kbase + j) == c ? 1.f : 0.f);
    h[j] = (_Float16)v;
  }
  *reinterpret_cast<half8*>(M + (((size_t)(b * 512 + c)) << 9) + kbase) = h;
}

// ---------- kernel 7: out = M_b . xT + sB — dbuf 2-phase, one barrier per step.
__global__ __launch_bounds__(256, 4) void k_tout(const _Float16* __restrict__ xT,
                                                 const _Float16* __restrict__ M,
                                                 const float* __restrict__ sB,
                                                 float* __restrict__ out) {
  __shared__ _Float16 lds[2][2][128 * 32];   // [buf][A/B], 8KB each = 32KB
  int wg = blockIdx.x;                 // 2048 blocks
  int id = (wg & 7) * 256 + (wg >> 3);
  int b = id >> 9;
  int rem = id & 511;
  int ct = rem >> 7;
  int ht = rem & 127;
  int tid = threadIdx.x;
  int wave = tid >> 6, lane = tid & 63, l15 = lane & 15, l4 = lane >> 4;
  int wr = wave >> 1, wc = wave & 1;
  const _Float16* Mb = M + ((size_t)b << 18);
  const _Float16* xTb = xT + (size_t)b * HW * CIN;

  int srow = lane >> 2;
  int gran = (lane & 3) ^ ((srow >> 1) & 3);
  const _Float16* gA[2];
  const _Float16* gB[2];
#pragma unroll
  for (int i = 0; i < 2; ++i) {
    int row = i * 64 + wave * 16 + srow;
    gA[i] = Mb + ((size_t)(ct * 128 + row) << 9) + gran * 8;
    gB[i] = xTb + ((size_t)(ht * 128 + row) << 9) + gran * 8;
  }

  int adA[4], adB[4];
#pragma unroll
  for (int rf = 0; rf < 4; ++rf) {
    int r = wr * 64 + rf * 16 + l15;
    adA[rf] = r * 64 + ((l4 ^ ((r >> 1) & 3)) << 4);
  }
#pragma unroll
  for (int cf = 0; cf < 4; ++cf) {
    int c = wc * 64 + cf * 16 + l15;
    adB[cf] = c * 64 + ((l4 ^ ((c >> 1) & 3)) << 4);
  }

  f32x4 acc[4][4];
#pragma unroll
  for (int rf = 0; rf < 4; ++rf)
#pragma unroll
    for (int cf = 0; cf < 4; ++cf) acc[rf][cf] = f32x4{0.f, 0.f, 0.f, 0.f};

  {
    char* dA = (char*)lds[0][0] + wave * 1024;
    char* dB = (char*)lds[0][1] + wave * 1024;
    gload_lds16(gA[0], dA);
    gload_lds16(gA[1], dA + 4096);
    gload_lds16(gB[0], dB);
    gload_lds16(gB[1], dB + 4096);
  }
  __syncthreads();

  for (int s = 0; s < 16; ++s) {
    if (s + 1 < 16) {
      int ko = (s + 1) * 32;
      char* dA = (char*)lds[(s + 1) & 1][0] + wave * 1024;
      char* dB = (char*)lds[(s + 1) & 1][1] + wave * 1024;
      gload_lds16(gA[0] + ko, dA);
      gload_lds16(gA[1] + ko, dA + 4096);
      gload_lds16(gB[0] + ko, dB);
      gload_lds16(gB[1] + ko, dB + 4096);
    }
    char* cA = (char*)lds[s & 1][0];
    char* cB = (char*)lds[s & 1][1];
    half8 af[4], bf[4];
#pragma unroll
    for (int rf = 0; rf < 4; ++rf) af[rf] = *reinterpret_cast<const half8*>(cA + adA[rf]);
#pragma unroll
    for (int cf = 0; cf < 4; ++cf) bf[cf] = *reinterpret_cast<const half8*>(cB + adB[cf]);
#pragma unroll
    for (int rf = 0; rf < 4; ++rf)
#pragma unroll
      for (int cf = 0; cf < 4; ++cf)
        acc[rf][cf] = __builtin_amdgcn_mfma_f32_16x16x32_f16(af[rf], bf[cf], acc[rf][cf], 0, 0, 0);
    __syncthreads();
  }

  size_t outb = ((size_t)b * CIN) << 14;
#pragma unroll
  for (int rf = 0; rf < 4; ++rf) {
#pragma unroll
    for (int r = 0; r < 4; ++r) {
      int c = ct * 128 + wr * 64 + rf * 16 + l4 * 4 + r;
      float bb = sB[b * CIN + c];
      size_t off = outb + ((size_t)c << 14) + ht * 128 + wc * 64 + l15;
#pragma unroll
      for (int cf = 0; cf < 4; ++cf)
        out[off + cf * 16] = acc[rf][cf][r] + bb;
    }
  }
}

// ---------- launch
extern "C" void kernel_launch(void* const* d_in, const int* in_sizes, int n_in,
                              void* d_out, int out_size, void* d_ws, size_t ws_size,
                              hipStream_t stream) {
  const float* x    = (const float*)d_in[0];
  const float* Wt   = (const float*)d_in[1];
  const float* Wp   = (const float*)d_in[2];
  const float* Wg   = (const float*)d_in[3];
  const float* Wz   = (const float*)d_in[4];
  const float* Wadj = (const float*)d_in[5];
  const float* bnag = (const float*)d_in[6];
  const float* bnab = (const float*)d_in[7];
  const float* bnam = (const float*)d_in[8];
  const float* bnav = (const float*)d_in[9];
  const float* Wwg  = (const float*)d_in[10];
  const float* bwgg = (const float*)d_in[11];
  const float* bwgb = (const float*)d_in[12];
  const float* bwgm = (const float*)d_in[13];
  const float* bwgv = (const float*)d_in[14];
  const float* gng  = (const float*)d_in[15];
  const float* gnb  = (const float*)d_in[16];

  char* ws = (char*)d_ws;
  _Float16* xT = (_Float16*)(ws);                      // 67108864
  float* GH   = (float*)(ws + 67371008);               // 4194304 (reused for M after k_sym)
  float* C1   = (float*)(ws + 71565312);               // 4194304
  float* Gs   = (float*)(ws + 75759616);               // 4194304
  float* V    = (float*)(ws + 79953920);               // 4194304
  float* xsum = (float*)(ws + 84148224);               // 8192
  float* att  = (float*)(ws + 84156416);               // 4096
  float* tsum = (float*)(ws + 84160512);               // 4096
  float* tsq  = (float*)(ws + 84164608);               // 4096
  float* sA   = (float*)(ws + 84168704);               // 8192
  float* sB   = (float*)(ws + 84176896);               // 8192
  if (ws_size < (size_t)84185088) return;
  _Float16* M = (_Float16*)GH;                         // GH dead after k_sym

  _Float16* Xh = (_Float16*)((char*)d_out);            // 67108864
  _Float16* Xl = (_Float16*)((char*)d_out + 67108864); // 67108864
  float* out = (float*)d_out;

  hipMemsetAsync(GH, 0, 8388608, stream);              // GH + C1 (contiguous)
  k_conv<<<dim3(2048), dim3(256), 0, stream>>>(x, Xh, Xl, xsum);
  k_xp16<<<dim3(256, 8, 4), dim3(256), 0, stream>>>(Xh, xT);
  k_gram<<<dim3(1664), dim3(256), 0, stream>>>(Xh, Xl, GH, C1);
  k_sym<<<dim3(8, 8, 4), dim3(256), 0, stream>>>(GH, C1, Gs);
  k_V<<<dim3(8, 8, 4), dim3(256), 0, stream>>>(Gs, Wg, Wt, V);
  k_red2<<<dim3(64), dim3(256), 0, stream>>>(V, xsum, Wp, Wt, att, tsum, tsq);
  k_graph<<<dim3(1), dim3(1024), 0, stream>>>(att, tsum, tsq, Wadj, bnag, bnab, bnam, bnav,
                                              Wwg, bwgg, bwgb, bwgm, bwgv, Wz, gng, gnb, sA, sB);
  k_M<<<dim3(512), dim3(256), 0, stream>>>(Wt, sA, M);
  k_tout<<<dim3(2048), dim3(256), 0, stream>>>(xT, M, sB, out);
}

// Round 15
// 263.447 us; speedup vs baseline: 1.1669x; 1.1669x over previous
//
#include <hip/hip_runtime.h>

#define HW 16384
#define CIN 512
#define PL 256
#define EPSF 1e-5f
#define SLO 0.0009765625f   // 2^-10

using half8  = __attribute__((ext_vector_type(8))) _Float16;
using half4v = __attribute__((ext_vector_type(4))) _Float16;
using f32x4  = __attribute__((ext_vector_type(4))) float;

__device__ inline void gload_lds16(const void* g, void* l) {
  __builtin_amdgcn_global_load_lds((const __attribute__((address_space(1))) void*)g,
                                   (__attribute__((address_space(3))) void*)l, 16, 0, 0);
}

// ---------- kernel 0: stream x -> Xh/Xl (row-major fp16 hi/lo) + xsum
__global__ __launch_bounds__(256) void k_conv(const float* __restrict__ x,
                                              _Float16* __restrict__ Xh,
                                              _Float16* __restrict__ Xl,
                                              float* __restrict__ xsum) {
  __shared__ float ws4[4];
  int row = blockIdx.x;                // b*512 + c
  int tid = threadIdx.x;
  const float* xr = x + ((size_t)row << 14);
  _Float16* hr = Xh + ((size_t)row << 14);
  _Float16* lr = Xl + ((size_t)row << 14);
  float s = 0.f;
#pragma unroll
  for (int j = 0; j < 8; ++j) {
    int o = j * 2048 + tid * 8;
    float4 v0 = *reinterpret_cast<const float4*>(xr + o);
    float4 v1 = *reinterpret_cast<const float4*>(xr + o + 4);
    half8 h, l;
    h[0] = (_Float16)v0.x; h[1] = (_Float16)v0.y; h[2] = (_Float16)v0.z; h[3] = (_Float16)v0.w;
    h[4] = (_Float16)v1.x; h[5] = (_Float16)v1.y; h[6] = (_Float16)v1.z; h[7] = (_Float16)v1.w;
    l[0] = (_Float16)((v0.x - (float)h[0]) * 1024.f);
    l[1] = (_Float16)((v0.y - (float)h[1]) * 1024.f);
    l[2] = (_Float16)((v0.z - (float)h[2]) * 1024.f);
    l[3] = (_Float16)((v0.w - (float)h[3]) * 1024.f);
    l[4] = (_Float16)((v1.x - (float)h[4]) * 1024.f);
    l[5] = (_Float16)((v1.y - (float)h[5]) * 1024.f);
    l[6] = (_Float16)((v1.z - (float)h[6]) * 1024.f);
    l[7] = (_Float16)((v1.w - (float)h[7]) * 1024.f);
    *reinterpret_cast<half8*>(hr + o) = h;
    *reinterpret_cast<half8*>(lr + o) = l;
    s += v0.x + v0.y + v0.z + v0.w + v1.x + v1.y + v1.z + v1.w;
  }
#pragma unroll
  for (int m = 1; m < 64; m <<= 1) s += __shfl_xor(s, m);
  if ((tid & 63) == 0) ws4[tid >> 6] = s;
  __syncthreads();
  if (tid == 0) xsum[row] = ws4[0] + ws4[1] + ws4[2] + ws4[3];
}

// ---------- kernel 1 (fused): blocks 0..831 = Gram (BK=64, 2-barrier, round-13 structure);
// blocks 832..9023 = fp16 transpose Xh -> xT (independent, backfills gram's bubbles/tail).
__global__ __launch_bounds__(256, 4) void k_gx(const _Float16* __restrict__ Xh,
                                               const _Float16* __restrict__ Xl,
                                               float* __restrict__ GH,
                                               float* __restrict__ C1,
                                               _Float16* __restrict__ xT) {
  __shared__ char smem[32768];
  int tid = threadIdx.x;

  if (blockIdx.x < 832) {
    // ---- Gram path ----
    _Float16* lA = (_Float16*)smem;            // 128*64 fp16 = 16KB
    _Float16* lB = (_Float16*)(smem + 16384);
    int wg = blockIdx.x;
    int id = (wg & 7) * 104 + (wg >> 3);       // XCD-chunked (832 % 8 == 0)
    int b = id / 208;
    int rem = id % 208;
    int ks = rem / 26;
    int u = rem % 26;
    int chain, ti, tj;
    if (u < 10) {
      chain = 0;
      ti = 0;
      while ((ti + 1) * (ti + 2) / 2 <= u) ++ti;
      tj = u - ti * (ti + 1) / 2;              // ti >= tj
    } else {
      chain = 1;
      int t = u - 10;
      ti = t >> 2; tj = t & 3;
    }
    int wave = tid >> 6, lane = tid & 63, l15 = lane & 15, l4 = lane >> 4;
    int wr = wave >> 1, wc = wave & 1;
    const _Float16* Asrc = (chain ? Xl : Xh) + (size_t)b * CIN * HW;
    const _Float16* Bsrc = Xh + (size_t)b * CIN * HW;
    float* D = chain ? C1 : GH;

    int srow = lane >> 3;
    int sgran = (lane & 7) ^ (srow & 7);
    int kbase = ks << 11;                      // chunk of 2048 elements
    const _Float16* gA[4];
    const _Float16* gB[4];
#pragma unroll
    for (int i = 0; i < 4; ++i) {
      int row = i * 32 + wave * 8 + srow;
      gA[i] = Asrc + (size_t)(ti * 128 + row) * HW + kbase + sgran * 8;
      gB[i] = Bsrc + (size_t)(tj * 128 + row) * HW + kbase + sgran * 8;
    }
    char* ldA = (char*)lA + wave * 1024;
    char* ldB = (char*)lB + wave * 1024;

    int adA[4][2], adB[4][2];
#pragma unroll
    for (int rf = 0; rf < 4; ++rf) {
      int r = wr * 64 + rf * 16 + l15;
#pragma unroll
      for (int ksub = 0; ksub < 2; ++ksub)
        adA[rf][ksub] = r * 128 + (((ksub * 4 + l4) ^ (r & 7)) << 4);
    }
#pragma unroll
    for (int cf = 0; cf < 4; ++cf) {
      int c = wc * 64 + cf * 16 + l15;
#pragma unroll
      for (int ksub = 0; ksub < 2; ++ksub)
        adB[cf][ksub] = c * 128 + (((ksub * 4 + l4) ^ (c & 7)) << 4);
    }

    f32x4 acc[4][4];
#pragma unroll
    for (int rf = 0; rf < 4; ++rf)
#pragma unroll
      for (int cf = 0; cf < 4; ++cf) acc[rf][cf] = f32x4{0.f, 0.f, 0.f, 0.f};

    for (int s = 0; s < 32; ++s) {
      int ko = s * 64;
#pragma unroll
      for (int i = 0; i < 4; ++i) {
        gload_lds16(gA[i] + ko, ldA + i * 4096);
        gload_lds16(gB[i] + ko, ldB + i * 4096);
      }
      __syncthreads();
#pragma unroll
      for (int ksub = 0; ksub < 2; ++ksub) {
        half8 af[4], bf[4];
#pragma unroll
        for (int rf = 0; rf < 4; ++rf)
          af[rf] = *reinterpret_cast<const half8*>((char*)lA + adA[rf][ksub]);
#pragma unroll
        for (int cf = 0; cf < 4; ++cf)
          bf[cf] = *reinterpret_cast<const half8*>((char*)lB + adB[cf][ksub]);
#pragma unroll
        for (int rf = 0; rf < 4; ++rf)
#pragma unroll
          for (int cf = 0; cf < 4; ++cf)
            acc[rf][cf] = __builtin_amdgcn_mfma_f32_16x16x32_f16(af[rf], bf[cf], acc[rf][cf], 0, 0, 0);
      }
      __syncthreads();
    }

    size_t bo = (size_t)b << 18;
#pragma unroll
    for (int rf = 0; rf < 4; ++rf)
#pragma unroll
      for (int cf = 0; cf < 4; ++cf)
#pragma unroll
        for (int r = 0; r < 4; ++r) {
          int i = ti * 128 + wr * 64 + rf * 16 + l4 * 4 + r;
          int j = tj * 128 + wc * 64 + cf * 16 + l15;
          atomicAdd(D + bo + ((size_t)i << 9) + j, acc[rf][cf][r]);
        }
  } else {
    // ---- transpose path: Xh [b][c][hw] -> xT [b][hw][c] ----
    _Float16* lds = (_Float16*)smem;           // 64*72 fp16 = 9216B
    int bid = blockIdx.x - 832;                // 0..8191
    int hw0 = (bid & 255) << 6;
    int c0 = ((bid >> 8) & 7) << 6;
    int b = bid >> 11;
    int rl = tid >> 3, seg = tid & 7;
    const _Float16* hb = Xh + ((size_t)b << 23);
#pragma unroll
    for (int pass = 0; pass < 2; ++pass) {
      int cl = pass * 32 + rl;
      half8 v = *reinterpret_cast<const half8*>(hb + ((size_t)(c0 + cl) << 14) + hw0 + seg * 8);
#pragma unroll
      for (int e = 0; e < 8; ++e) lds[(seg * 8 + e) * 72 + cl] = v[e];
    }
    __syncthreads();
    _Float16* tb = xT + (((size_t)b << 14) + hw0) * CIN + c0;
#pragma unroll
    for (int pass = 0; pass < 2; ++pass) {
      int hwl = pass * 32 + rl;
      half8 o = *reinterpret_cast<const half8*>(&lds[hwl * 72 + seg * 8]);
      *reinterpret_cast<half8*>(tb + (size_t)hwl * CIN + seg * 8) = o;
    }
  }
}

// ---------- kernel 2: Gs[i][j] = GHs[i][j] + SLO*(C1[i][j] + C1[j][i]);
__global__ __launch_bounds__(256) void k_sym(const float* __restrict__ GH,
                                             const float* __restrict__ C1,
                                             float* __restrict__ Gs) {
  __shared__ float T1[64 * 65];
  __shared__ float TG[64 * 65];
  int I = blockIdx.x, J = blockIdx.y, b = blockIdx.z;
  int i0 = I << 6, j0 = J << 6;
  bool upper = (I >> 1) >= (J >> 1);
  size_t bo = (size_t)b << 18;
  int tid = threadIdx.x;
  int r = tid >> 2, cs = (tid & 3) << 4;
#pragma unroll
  for (int u = 0; u < 16; u += 4) {
    size_t toff = bo + (((size_t)(j0 + r)) << 9) + i0 + cs + u;
    float4 v = *reinterpret_cast<const float4*>(C1 + toff);
    T1[r * 65 + cs + u + 0] = v.x; T1[r * 65 + cs + u + 1] = v.y;
    T1[r * 65 + cs + u + 2] = v.z; T1[r * 65 + cs + u + 3] = v.w;
    if (!upper) {
      float4 g = *reinterpret_cast<const float4*>(GH + toff);
      TG[r * 65 + cs + u + 0] = g.x; TG[r * 65 + cs + u + 1] = g.y;
      TG[r * 65 + cs + u + 2] = g.z; TG[r * 65 + cs + u + 3] = g.w;
    }
  }
  __syncthreads();
#pragma unroll
  for (int u = 0; u < 16; u += 4) {
    size_t off = bo + (((size_t)(i0 + r)) << 9) + j0 + cs + u;
    float4 c = *reinterpret_cast<const float4*>(C1 + off);
    float t0 = T1[(cs + u + 0) * 65 + r];
    float t1 = T1[(cs + u + 1) * 65 + r];
    float t2 = T1[(cs + u + 2) * 65 + r];
    float t3 = T1[(cs + u + 3) * 65 + r];
    float4 o;
    if (upper) {
      float4 h = *reinterpret_cast<const float4*>(GH + off);
      o.x = h.x + SLO * (c.x + t0);
      o.y = h.y + SLO * (c.y + t1);
      o.z = h.z + SLO * (c.z + t2);
      o.w = h.w + SLO * (c.w + t3);
    } else {
      o.x = TG[(cs + u + 0) * 65 + r] + SLO * (c.x + t0);
      o.y = TG[(cs + u + 1) * 65 + r] + SLO * (c.y + t1);
      o.z = TG[(cs + u + 2) * 65 + r] + SLO * (c.z + t2);
      o.w = TG[(cs + u + 3) * 65 + r] + SLO * (c.w + t3);
    }
    *reinterpret_cast<float4*>(Gs + off) = o;
  }
}

// ---------- kernel 3: V[b][ocol][i] = sum_j W[ocol][j] * Gs[b][i][j]
__global__ __launch_bounds__(256) void k_V(const float* __restrict__ Gs,
                                           const float* __restrict__ Wg,
                                           const float* __restrict__ Wt,
                                           float* __restrict__ V) {
  __shared__ float Gl[64 * 65];
  __shared__ float Wl[64 * 65];
  int it = blockIdx.x, ot = blockIdx.y, b = blockIdx.z;
  int i0 = it << 6, o0 = ot << 6;
  int tid = threadIdx.x;
  int srow = tid >> 2, sseg = (tid & 3) << 4;
  const float* gsb = Gs + ((size_t)b << 18);
  int orow = o0 + srow;
  const float* wrow = (orow < 256) ? (Wg + (size_t)orow * 512) : (Wt + (size_t)(orow - 256) * 512);
  float acc[4][4];
#pragma unroll
  for (int a = 0; a < 4; ++a)
#pragma unroll
    for (int c = 0; c < 4; ++c) acc[a][c] = 0.f;
  int oy = (tid >> 4) << 2, ix = (tid & 15) << 2;
  for (int jc = 0; jc < 512; jc += 64) {
    __syncthreads();
#pragma unroll
    for (int u = 0; u < 16; u += 4) {
      float4 g = *reinterpret_cast<const float4*>(gsb + ((size_t)(i0 + srow) << 9) + jc + sseg + u);
      float4 w = *reinterpret_cast<const float4*>(wrow + jc + sseg + u);
      Gl[srow * 65 + sseg + u + 0] = g.x; Gl[srow * 65 + sseg + u + 1] = g.y;
      Gl[srow * 65 + sseg + u + 2] = g.z; Gl[srow * 65 + sseg + u + 3] = g.w;
      Wl[srow * 65 + sseg + u + 0] = w.x; Wl[srow * 65 + sseg + u + 1] = w.y;
      Wl[srow * 65 + sseg + u + 2] = w.z; Wl[srow * 65 + sseg + u + 3] = w.w;
    }
    __syncthreads();
    for (int j = 0; j < 64; ++j) {
      float w0 = Wl[(oy + 0) * 65 + j], w1 = Wl[(oy + 1) * 65 + j];
      float w2 = Wl[(oy + 2) * 65 + j], w3 = Wl[(oy + 3) * 65 + j];
      float g0 = Gl[(ix + 0) * 65 + j], g1 = Gl[(ix + 1) * 65 + j];
      float g2 = Gl[(ix + 2) * 65 + j], g3 = Gl[(ix + 3) * 65 + j];
      acc[0][0] += w0 * g0; acc[0][1] += w0 * g1; acc[0][2] += w0 * g2; acc[0][3] += w0 * g3;
      acc[1][0] += w1 * g0; acc[1][1] += w1 * g1; acc[1][2] += w1 * g2; acc[1][3] += w1 * g3;
      acc[2][0] += w2 * g0; acc[2][1] += w2 * g1; acc[2][2] += w2 * g2; acc[2][3] += w2 * g3;
      acc[3][0] += w3 * g0; acc[3][1] += w3 * g1; acc[3][2] += w3 * g2; acc[3][3] += w3 * g3;
    }
  }
  float* vb = V + ((size_t)b << 18);
#pragma unroll
  for (int a = 0; a < 4; ++a) {
    float4 vv = {acc[a][0], acc[a][1], acc[a][2], acc[a][3]};
    *reinterpret_cast<float4*>(vb + ((size_t)(o0 + oy + a) << 9) + i0 + ix) = vv;
  }
}

// ---------- kernel 4: att/tsq/tsum per (b,o)
__global__ __launch_bounds__(256) void k_red2(const float* __restrict__ V,
                                              const float* __restrict__ xsum,
                                              const float* __restrict__ Wp,
                                              const float* __restrict__ Wt,
                                              float* __restrict__ att,
                                              float* __restrict__ tsum,
                                              float* __restrict__ tsq) {
  int blk = blockIdx.x;
  int b = blk >> 4;
  int og = (blk & 15) << 4;
  int tid = threadIdx.x;
  int ol = tid >> 4, seg = tid & 15;
  int o = og + ol;
  const float* vg = V + ((size_t)b << 18) + ((size_t)o << 9) + seg * 32;
  const float* vt = V + ((size_t)b << 18) + ((size_t)(256 + o) << 9) + seg * 32;
  const float* wp = Wp + (size_t)o * 512 + seg * 32;
  const float* wt = Wt + (size_t)o * 512 + seg * 32;
  const float* xs = xsum + b * CIN + seg * 32;
  float sa = 0.f, sq = 0.f, sm = 0.f;
#pragma unroll
  for (int i = 0; i < 32; i += 4) {
    float4 a = *reinterpret_cast<const float4*>(vg + i);
    float4 p = *reinterpret_cast<const float4*>(wp + i);
    float4 c = *reinterpret_cast<const float4*>(vt + i);
    float4 t = *reinterpret_cast<const float4*>(wt + i);
    float4 s = *reinterpret_cast<const float4*>(xs + i);
    sa += a.x * p.x + a.y * p.y + a.z * p.z + a.w * p.w;
    sq += c.x * t.x + c.y * t.y + c.z * t.z + c.w * t.w;
    sm += t.x * s.x + t.y * s.y + t.z * s.z + t.w * s.w;
  }
#pragma unroll
  for (int m = 1; m < 16; m <<= 1) {
    sa += __shfl_xor(sa, m);
    sq += __shfl_xor(sq, m);
    sm += __shfl_xor(sm, m);
  }
  if (seg == 0) {
    att[b * PL + o] = sa;
    tsq[b * PL + o] = sq;
    tsum[b * PL + o] = sm;
  }
}

// ---------- kernel 5: graph math (one block, 1024 threads)
__global__ __launch_bounds__(1024) void k_graph(
    const float* __restrict__ att, const float* __restrict__ tsum, const float* __restrict__ tsq,
    const float* __restrict__ W_adj, const float* __restrict__ bnag, const float* __restrict__ bnab,
    const float* __restrict__ bnam, const float* __restrict__ bnav,
    const float* __restrict__ W_wg, const float* __restrict__ bwgg, const float* __restrict__ bwgb,
    const float* __restrict__ bwgm, const float* __restrict__ bwgv,
    const float* __restrict__ Wz, const float* __restrict__ gng, const float* __restrict__ gnb,
    float* __restrict__ sA, float* __restrict__ sB) {
  __shared__ float att_l[4 * 256];
  __shared__ float z_l[4 * 256];
  __shared__ float zv_l[4 * 256];
  int tid = threadIdx.x;
  att_l[tid] = att[tid];
  __syncthreads();
  int b = tid >> 8, r = tid & 255, i = r >> 3, k = r & 7;
  float z1 = 0.f;
#pragma unroll
  for (int m = 0; m < 32; ++m) z1 += W_adj[i * 32 + m] * att_l[b * 256 + k * 32 + m];
  float inv = rsqrtf(bnav[i] + EPSF);
  float z = (z1 - bnam[i]) * inv * bnag[i] + bnab[i];
  z = fmaxf(z, 0.f) + att_l[b * 256 + k * 32 + i];
  z_l[b * 256 + i * 8 + k] = z;
  __syncthreads();
  float z2 = 0.f;
#pragma unroll
  for (int e = 0; e < 8; ++e) z2 += W_wg[k * 8 + e] * z_l[b * 256 + i * 8 + e];
  float inv2 = rsqrtf(bwgv[k] + EPSF);
  z2 = (z2 - bwgm[k]) * inv2 * bwgg[k] + bwgb[k];
  zv_l[b * 256 + i * 8 + k] = fmaxf(z2, 0.f);
  __syncthreads();
  int g = r;
  float s = zv_l[b * 256 + g];
  float m1 = tsum[b * 256 + g] * (1.f / 16384.f);
  float m2 = tsq[b * 256 + g] * (1.f / 16384.f);
  float a0 = Wz[2 * g] * s, a1 = Wz[2 * g + 1] * s;
  float mu = 0.5f * (a0 + a1) * m1;
  float ey2 = 0.5f * (a0 * a0 + a1 * a1) * m2;
  float var = ey2 - mu * mu;
  float invg = rsqrtf(var + EPSF);
  int c = b * CIN + 2 * g;
  sA[c]     = a0 * invg * gng[2 * g];
  sA[c + 1] = a1 * invg * gng[2 * g + 1];
  sB[c]     = gnb[2 * g]     - mu * invg * gng[2 * g];
  sB[c + 1] = gnb[2 * g + 1] - mu * invg * gng[2 * g + 1];
}

// ---------- kernel 6: M[b][c][k] = fp16(sA[b,c]*Wt[c>>1][k] + (c==k))
__global__ __launch_bounds__(256) void k_M(const float* __restrict__ Wt,
                                           const float* __restrict__ sA,
                                           _Float16* __restrict__ M) {
  int idx = blockIdx.x * 256 + threadIdx.x;
  int k8 = idx & 63;
  int c = (idx >> 6) & 511;
  int b = idx >> 15;
  float s = sA[b * 512 + c];
  const float* wrow = Wt + ((size_t)(c >> 1) << 9) + k8 * 8;
  int kbase = k8 * 8;
  half8 h;
#pragma unroll
  for (int j = 0; j < 8; ++j) {
    float v = s * wrow[j] + ((kbase + j) == c ? 1.f : 0.f);
    h[j] = (_Float16)v;
  }
  *reinterpret_cast<half8*>(M + (((size_t)(b * 512 + c)) << 9) + kbase) = h;
}

// ---------- kernel 7: out = M_b . xT + sB — m97 structure (round-13 version).
__global__ __launch_bounds__(256, 4) void k_tout(const _Float16* __restrict__ xT,
                                                 const _Float16* __restrict__ M,
                                                 const float* __restrict__ sB,
                                                 float* __restrict__ out) {
  __shared__ _Float16 lA[128 * 32];
  __shared__ _Float16 lB[128 * 32];
  int wg = blockIdx.x;                 // 2048 blocks
  int id = (wg & 7) * 256 + (wg >> 3);
  int b = id >> 9;
  int rem = id & 511;
  int ct = rem >> 7;
  int ht = rem & 127;
  int tid = threadIdx.x;
  int wave = tid >> 6, lane = tid & 63, l15 = lane & 15, l4 = lane >> 4;
  int wr = wave >> 1, wc = wave & 1;
  const _Float16* Mb = M + ((size_t)b << 18);
  const _Float16* xTb = xT + (size_t)b * HW * CIN;

  int srow = lane >> 2;
  int gran = (lane & 3) ^ ((srow >> 1) & 3);
  const _Float16* gA[2];
  const _Float16* gB[2];
#pragma unroll
  for (int i = 0; i < 2; ++i) {
    int row = i * 64 + wave * 16 + srow;
    gA[i] = Mb + ((size_t)(ct * 128 + row) << 9) + gran * 8;
    gB[i] = xTb + ((size_t)(ht * 128 + row) << 9) + gran * 8;
  }
  char* ldA = (char*)lA + wave * 1024;
  char* ldB = (char*)lB + wave * 1024;

  int adA[4], adB[4];
#pragma unroll
  for (int rf = 0; rf < 4; ++rf) {
    int r = wr * 64 + rf * 16 + l15;
    adA[rf] = r * 64 + ((l4 ^ ((r >> 1) & 3)) << 4);
  }
#pragma unroll
  for (int cf = 0; cf < 4; ++cf) {
    int c = wc * 64 + cf * 16 + l15;
    adB[cf] = c * 64 + ((l4 ^ ((c >> 1) & 3)) << 4);
  }

  f32x4 acc[4][4];
#pragma unroll
  for (int rf = 0; rf < 4; ++rf)
#pragma unroll
    for (int cf = 0; cf < 4; ++cf) acc[rf][cf] = f32x4{0.f, 0.f, 0.f, 0.f};

  for (int s = 0; s < 16; ++s) {
    int ko = s * 32;
    gload_lds16(gA[0] + ko, ldA);
    gload_lds16(gA[1] + ko, ldA + 4096);
    gload_lds16(gB[0] + ko, ldB);
    gload_lds16(gB[1] + ko, ldB + 4096);
    __syncthreads();
    half8 af[4], bf[4];
#pragma unroll
    for (int rf = 0; rf < 4; ++rf) af[rf] = *reinterpret_cast<const half8*>((char*)lA + adA[rf]);
#pragma unroll
    for (int cf = 0; cf < 4; ++cf) bf[cf] = *reinterpret_cast<const half8*>((char*)lB + adB[cf]);
#pragma unroll
    for (int rf = 0; rf < 4; ++rf)
#pragma unroll
      for (int cf = 0; cf < 4; ++cf)
        acc[rf][cf] = __builtin_amdgcn_mfma_f32_16x16x32_f16(af[rf], bf[cf], acc[rf][cf], 0, 0, 0);
    __syncthreads();
  }

  size_t outb = ((size_t)b * CIN) << 14;
#pragma unroll
  for (int rf = 0; rf < 4; ++rf) {
#pragma unroll
    for (int r = 0; r < 4; ++r) {
      int c = ct * 128 + wr * 64 + rf * 16 + l4 * 4 + r;
      float bb = sB[b * CIN + c];
      size_t off = outb + ((size_t)c << 14) + ht * 128 + wc * 64 + l15;
#pragma unroll
      for (int cf = 0; cf < 4; ++cf)
        out[off + cf * 16] = acc[rf][cf][r] + bb;
    }
  }
}

// ---------- launch
extern "C" void kernel_launch(void* const* d_in, const int* in_sizes, int n_in,
                              void* d_out, int out_size, void* d_ws, size_t ws_size,
                              hipStream_t stream) {
  const float* x    = (const float*)d_in[0];
  const float* Wt   = (const float*)d_in[1];
  const float* Wp   = (const float*)d_in[2];
  const float* Wg   = (const float*)d_in[3];
  const float* Wz   = (const float*)d_in[4];
  const float* Wadj = (const float*)d_in[5];
  const float* bnag = (const float*)d_in[6];
  const float* bnab = (const float*)d_in[7];
  const float* bnam = (const float*)d_in[8];
  const float* bnav = (const float*)d_in[9];
  const float* Wwg  = (const float*)d_in[10];
  const float* bwgg = (const float*)d_in[11];
  const float* bwgb = (const float*)d_in[12];
  const float* bwgm = (const float*)d_in[13];
  const float* bwgv = (const float*)d_in[14];
  const float* gng  = (const float*)d_in[15];
  const float* gnb  = (const float*)d_in[16];

  char* ws = (char*)d_ws;
  _Float16* xT = (_Float16*)(ws);                      // 67108864
  float* GH   = (float*)(ws + 67371008);               // 4194304 (reused for M after k_sym)
  float* C1   = (float*)(ws + 71565312);               // 4194304
  float* Gs   = (float*)(ws + 75759616);               // 4194304
  float* V    = (float*)(ws + 79953920);               // 4194304
  float* xsum = (float*)(ws + 84148224);               // 8192
  float* att  = (float*)(ws + 84156416);               // 4096
  float* tsum = (float*)(ws + 84160512);               // 4096
  float* tsq  = (float*)(ws + 84164608);               // 4096
  float* sA   = (float*)(ws + 84168704);               // 8192
  float* sB   = (float*)(ws + 84176896);               // 8192
  if (ws_size < (size_t)84185088) return;
  _Float16* M = (_Float16*)GH;                         // GH dead after k_sym

  _Float16* Xh = (_Float16*)((char*)d_out);            // 67108864
  _Float16* Xl = (_Float16*)((char*)d_out + 67108864); // 67108864
  float* out = (float*)d_out;

  hipMemsetAsync(GH, 0, 8388608, stream);              // GH + C1 (contiguous)
  k_conv<<<dim3(2048), dim3(256), 0, stream>>>(x, Xh, Xl, xsum);
  k_gx<<<dim3(9024), dim3(256), 0, stream>>>(Xh, Xl, GH, C1, xT);
  k_sym<<<dim3(8, 8, 4), dim3(256), 0, stream>>>(GH, C1, Gs);
  k_V<<<dim3(8, 8, 4), dim3(256), 0, stream>>>(Gs, Wg, Wt, V);
  k_red2<<<dim3(64), dim3(256), 0, stream>>>(V, xsum, Wp, Wt, att, tsum, tsq);
  k_graph<<<dim3(1), dim3(1024), 0, stream>>>(att, tsum, tsq, Wadj, bnag, bnab, bnam, bnav,
                                              Wwg, bwgg, bwgb, bwgm, bwgv, Wz, gng, gnb, sA, sB);
  k_M<<<dim3(512), dim3(256), 0, stream>>>(Wt, sA, M);
  k_tout<<<dim3(2048), dim3(256), 0, stream>>>(xT, M, sB, out);
}

// Round 16
// 262.508 us; speedup vs baseline: 1.1710x; 1.0036x over previous
//
#include <hip/hip_runtime.h>

#define HW 16384
#define CIN 512
#define PL 256
#define EPSF 1e-5f
#define SLO 0.0009765625f   // 2^-10

using half8  = __attribute__((ext_vector_type(8))) _Float16;
using half4v = __attribute__((ext_vector_type(4))) _Float16;
using f32x4  = __attribute__((ext_vector_type(4))) float;

__device__ inline void gload_lds16(const void* g, void* l) {
  __builtin_amdgcn_global_load_lds((const __attribute__((address_space(1))) void*)g,
                                   (__attribute__((address_space(3))) void*)l, 16, 0, 0);
}

// ---------- kernel 0: stream x -> Xh/Xl (row-major fp16 hi/lo) + xsum
__global__ __launch_bounds__(256) void k_conv(const float* __restrict__ x,
                                              _Float16* __restrict__ Xh,
                                              _Float16* __restrict__ Xl,
                                              float* __restrict__ xsum) {
  __shared__ float ws4[4];
  int row = blockIdx.x;                // b*512 + c
  int tid = threadIdx.x;
  const float* xr = x + ((size_t)row << 14);
  _Float16* hr = Xh + ((size_t)row << 14);
  _Float16* lr = Xl + ((size_t)row << 14);
  float s = 0.f;
#pragma unroll
  for (int j = 0; j < 8; ++j) {
    int o = j * 2048 + tid * 8;
    float4 v0 = *reinterpret_cast<const float4*>(xr + o);
    float4 v1 = *reinterpret_cast<const float4*>(xr + o + 4);
    half8 h, l;
    h[0] = (_Float16)v0.x; h[1] = (_Float16)v0.y; h[2] = (_Float16)v0.z; h[3] = (_Float16)v0.w;
    h[4] = (_Float16)v1.x; h[5] = (_Float16)v1.y; h[6] = (_Float16)v1.z; h[7] = (_Float16)v1.w;
    l[0] = (_Float16)((v0.x - (float)h[0]) * 1024.f);
    l[1] = (_Float16)((v0.y - (float)h[1]) * 1024.f);
    l[2] = (_Float16)((v0.z - (float)h[2]) * 1024.f);
    l[3] = (_Float16)((v0.w - (float)h[3]) * 1024.f);
    l[4] = (_Float16)((v1.x - (float)h[4]) * 1024.f);
    l[5] = (_Float16)((v1.y - (float)h[5]) * 1024.f);
    l[6] = (_Float16)((v1.z - (float)h[6]) * 1024.f);
    l[7] = (_Float16)((v1.w - (float)h[7]) * 1024.f);
    *reinterpret_cast<half8*>(hr + o) = h;
    *reinterpret_cast<half8*>(lr + o) = l;
    s += v0.x + v0.y + v0.z + v0.w + v1.x + v1.y + v1.z + v1.w;
  }
#pragma unroll
  for (int m = 1; m < 64; m <<= 1) s += __shfl_xor(s, m);
  if ((tid & 63) == 0) ws4[tid >> 6] = s;
  __syncthreads();
  if (tid == 0) xsum[row] = ws4[0] + ws4[1] + ws4[2] + ws4[3];
}

// ---------- kernel 1 (fused): blocks 0..831 = Gram (BK=64, 2-barrier);
// blocks 832..9023 = fp16 transpose Xh -> xT with granule-XOR swizzle (conflict-free).
__global__ __launch_bounds__(256, 4) void k_gx(const _Float16* __restrict__ Xh,
                                               const _Float16* __restrict__ Xl,
                                               float* __restrict__ GH,
                                               float* __restrict__ C1,
                                               _Float16* __restrict__ xT) {
  __shared__ char smem[32768];
  int tid = threadIdx.x;

  if (blockIdx.x < 832) {
    // ---- Gram path (round-13 BK=64 structure, verified) ----
    _Float16* lA = (_Float16*)smem;            // 128*64 fp16 = 16KB
    _Float16* lB = (_Float16*)(smem + 16384);
    int wg = blockIdx.x;
    int id = (wg & 7) * 104 + (wg >> 3);       // XCD-chunked (832 % 8 == 0)
    int b = id / 208;
    int rem = id % 208;
    int ks = rem / 26;
    int u = rem % 26;
    int chain, ti, tj;
    if (u < 10) {
      chain = 0;
      ti = 0;
      while ((ti + 1) * (ti + 2) / 2 <= u) ++ti;
      tj = u - ti * (ti + 1) / 2;              // ti >= tj
    } else {
      chain = 1;
      int t = u - 10;
      ti = t >> 2; tj = t & 3;
    }
    int wave = tid >> 6, lane = tid & 63, l15 = lane & 15, l4 = lane >> 4;
    int wr = wave >> 1, wc = wave & 1;
    const _Float16* Asrc = (chain ? Xl : Xh) + (size_t)b * CIN * HW;
    const _Float16* Bsrc = Xh + (size_t)b * CIN * HW;
    float* D = chain ? C1 : GH;

    int srow = lane >> 3;
    int sgran = (lane & 7) ^ (srow & 7);
    int kbase = ks << 11;                      // chunk of 2048 elements
    const _Float16* gA[4];
    const _Float16* gB[4];
#pragma unroll
    for (int i = 0; i < 4; ++i) {
      int row = i * 32 + wave * 8 + srow;
      gA[i] = Asrc + (size_t)(ti * 128 + row) * HW + kbase + sgran * 8;
      gB[i] = Bsrc + (size_t)(tj * 128 + row) * HW + kbase + sgran * 8;
    }
    char* ldA = (char*)lA + wave * 1024;
    char* ldB = (char*)lB + wave * 1024;

    int adA[4][2], adB[4][2];
#pragma unroll
    for (int rf = 0; rf < 4; ++rf) {
      int r = wr * 64 + rf * 16 + l15;
#pragma unroll
      for (int ksub = 0; ksub < 2; ++ksub)
        adA[rf][ksub] = r * 128 + (((ksub * 4 + l4) ^ (r & 7)) << 4);
    }
#pragma unroll
    for (int cf = 0; cf < 4; ++cf) {
      int c = wc * 64 + cf * 16 + l15;
#pragma unroll
      for (int ksub = 0; ksub < 2; ++ksub)
        adB[cf][ksub] = c * 128 + (((ksub * 4 + l4) ^ (c & 7)) << 4);
    }

    f32x4 acc[4][4];
#pragma unroll
    for (int rf = 0; rf < 4; ++rf)
#pragma unroll
      for (int cf = 0; cf < 4; ++cf) acc[rf][cf] = f32x4{0.f, 0.f, 0.f, 0.f};

    for (int s = 0; s < 32; ++s) {
      int ko = s * 64;
#pragma unroll
      for (int i = 0; i < 4; ++i) {
        gload_lds16(gA[i] + ko, ldA + i * 4096);
        gload_lds16(gB[i] + ko, ldB + i * 4096);
      }
      __syncthreads();
#pragma unroll
      for (int ksub = 0; ksub < 2; ++ksub) {
        half8 af[4], bf[4];
#pragma unroll
        for (int rf = 0; rf < 4; ++rf)
          af[rf] = *reinterpret_cast<const half8*>((char*)lA + adA[rf][ksub]);
#pragma unroll
        for (int cf = 0; cf < 4; ++cf)
          bf[cf] = *reinterpret_cast<const half8*>((char*)lB + adB[cf][ksub]);
#pragma unroll
        for (int rf = 0; rf < 4; ++rf)
#pragma unroll
          for (int cf = 0; cf < 4; ++cf)
            acc[rf][cf] = __builtin_amdgcn_mfma_f32_16x16x32_f16(af[rf], bf[cf], acc[rf][cf], 0, 0, 0);
      }
      __syncthreads();
    }

    size_t bo = (size_t)b << 18;
#pragma unroll
    for (int rf = 0; rf < 4; ++rf)
#pragma unroll
      for (int cf = 0; cf < 4; ++cf)
#pragma unroll
        for (int r = 0; r < 4; ++r) {
          int i = ti * 128 + wr * 64 + rf * 16 + l4 * 4 + r;
          int j = tj * 128 + wc * 64 + cf * 16 + l15;
          atomicAdd(D + bo + ((size_t)i << 9) + j, acc[rf][cf][r]);
        }
  } else {
    // ---- transpose path: Xh [b][c][hw] -> xT [b][hw][c], granule-XOR swizzled LDS ----
    // LDS tile [64 hw][72 c-stride]; element (r=hw_local, cl=c_local) stored with its 8-col
    // chunk relocated to chunk' = (cl>>3) ^ ((r>>3)&7). Writes & reads both conflict-free.
    _Float16* lds = (_Float16*)smem;           // 64*72 fp16 = 9216B
    int bid = blockIdx.x - 832;                // 0..8191
    int hw0 = (bid & 255) << 6;
    int c0 = ((bid >> 8) & 7) << 6;
    int b = bid >> 11;
    int rl = tid >> 3, seg = tid & 7;
    const _Float16* hb = Xh + ((size_t)b << 23);
#pragma unroll
    for (int pass = 0; pass < 2; ++pass) {
      int cl = pass * 32 + rl;
      int chunk = cl >> 3, wi = cl & 7;
      half8 v = *reinterpret_cast<const half8*>(hb + ((size_t)(c0 + cl) << 14) + hw0 + seg * 8);
#pragma unroll
      for (int e = 0; e < 8; ++e) {
        int r = seg * 8 + e;
        lds[r * 72 + ((chunk ^ ((r >> 3) & 7)) << 3) + wi] = v[e];
      }
    }
    __syncthreads();
    _Float16* tb = xT + (((size_t)b << 14) + hw0) * CIN + c0;
#pragma unroll
    for (int pass = 0; pass < 2; ++pass) {
      int hwl = pass * 32 + rl;
      int chp = seg ^ ((hwl >> 3) & 7);
      half8 o = *reinterpret_cast<const half8*>(&lds[hwl * 72 + (chp << 3)]);
      *reinterpret_cast<half8*>(tb + (size_t)hwl * CIN + seg * 8) = o;
    }
  }
}

// ---------- kernel 2: Gs[i][j] = GHs[i][j] + SLO*(C1[i][j] + C1[j][i]);
__global__ __launch_bounds__(256) void k_sym(const float* __restrict__ GH,
                                             const float* __restrict__ C1,
                                             float* __restrict__ Gs) {
  __shared__ float T1[64 * 65];
  __shared__ float TG[64 * 65];
  int I = blockIdx.x, J = blockIdx.y, b = blockIdx.z;
  int i0 = I << 6, j0 = J << 6;
  bool upper = (I >> 1) >= (J >> 1);
  size_t bo = (size_t)b << 18;
  int tid = threadIdx.x;
  int r = tid >> 2, cs = (tid & 3) << 4;
#pragma unroll
  for (int u = 0; u < 16; u += 4) {
    size_t toff = bo + (((size_t)(j0 + r)) << 9) + i0 + cs + u;
    float4 v = *reinterpret_cast<const float4*>(C1 + toff);
    T1[r * 65 + cs + u + 0] = v.x; T1[r * 65 + cs + u + 1] = v.y;
    T1[r * 65 + cs + u + 2] = v.z; T1[r * 65 + cs + u + 3] = v.w;
    if (!upper) {
      float4 g = *reinterpret_cast<const float4*>(GH + toff);
      TG[r * 65 + cs + u + 0] = g.x; TG[r * 65 + cs + u + 1] = g.y;
      TG[r * 65 + cs + u + 2] = g.z; TG[r * 65 + cs + u + 3] = g.w;
    }
  }
  __syncthreads();
#pragma unroll
  for (int u = 0; u < 16; u += 4) {
    size_t off = bo + (((size_t)(i0 + r)) << 9) + j0 + cs + u;
    float4 c = *reinterpret_cast<const float4*>(C1 + off);
    float t0 = T1[(cs + u + 0) * 65 + r];
    float t1 = T1[(cs + u + 1) * 65 + r];
    float t2 = T1[(cs + u + 2) * 65 + r];
    float t3 = T1[(cs + u + 3) * 65 + r];
    float4 o;
    if (upper) {
      float4 h = *reinterpret_cast<const float4*>(GH + off);
      o.x = h.x + SLO * (c.x + t0);
      o.y = h.y + SLO * (c.y + t1);
      o.z = h.z + SLO * (c.z + t2);
      o.w = h.w + SLO * (c.w + t3);
    } else {
      o.x = TG[(cs + u + 0) * 65 + r] + SLO * (c.x + t0);
      o.y = TG[(cs + u + 1) * 65 + r] + SLO * (c.y + t1);
      o.z = TG[(cs + u + 2) * 65 + r] + SLO * (c.z + t2);
      o.w = TG[(cs + u + 3) * 65 + r] + SLO * (c.w + t3);
    }
    *reinterpret_cast<float4*>(Gs + off) = o;
  }
}

// ---------- kernel 3: V[b][ocol][i] = sum_j W[ocol][j] * Gs[b][i][j]
__global__ __launch_bounds__(256) void k_V(const float* __restrict__ Gs,
                                           const float* __restrict__ Wg,
                                           const float* __restrict__ Wt,
                                           float* __restrict__ V) {
  __shared__ float Gl[64 * 65];
  __shared__ float Wl[64 * 65];
  int it = blockIdx.x, ot = blockIdx.y, b = blockIdx.z;
  int i0 = it << 6, o0 = ot << 6;
  int tid = threadIdx.x;
  int srow = tid >> 2, sseg = (tid & 3) << 4;
  const float* gsb = Gs + ((size_t)b << 18);
  int orow = o0 + srow;
  const float* wrow = (orow < 256) ? (Wg + (size_t)orow * 512) : (Wt + (size_t)(orow - 256) * 512);
  float acc[4][4];
#pragma unroll
  for (int a = 0; a < 4; ++a)
#pragma unroll
    for (int c = 0; c < 4; ++c) acc[a][c] = 0.f;
  int oy = (tid >> 4) << 2, ix = (tid & 15) << 2;
  for (int jc = 0; jc < 512; jc += 64) {
    __syncthreads();
#pragma unroll
    for (int u = 0; u < 16; u += 4) {
      float4 g = *reinterpret_cast<const float4*>(gsb + ((size_t)(i0 + srow) << 9) + jc + sseg + u);
      float4 w = *reinterpret_cast<const float4*>(wrow + jc + sseg + u);
      Gl[srow * 65 + sseg + u + 0] = g.x; Gl[srow * 65 + sseg + u + 1] = g.y;
      Gl[srow * 65 + sseg + u + 2] = g.z; Gl[srow * 65 + sseg + u + 3] = g.w;
      Wl[srow * 65 + sseg + u + 0] = w.x; Wl[srow * 65 + sseg + u + 1] = w.y;
      Wl[srow * 65 + sseg + u + 2] = w.z; Wl[srow * 65 + sseg + u + 3] = w.w;
    }
    __syncthreads();
    for (int j = 0; j < 64; ++j) {
      float w0 = Wl[(oy + 0) * 65 + j], w1 = Wl[(oy + 1) * 65 + j];
      float w2 = Wl[(oy + 2) * 65 + j], w3 = Wl[(oy + 3) * 65 + j];
      float g0 = Gl[(ix + 0) * 65 + j], g1 = Gl[(ix + 1) * 65 + j];
      float g2 = Gl[(ix + 2) * 65 + j], g3 = Gl[(ix + 3) * 65 + j];
      acc[0][0] += w0 * g0; acc[0][1] += w0 * g1; acc[0][2] += w0 * g2; acc[0][3] += w0 * g3;
      acc[1][0] += w1 * g0; acc[1][1] += w1 * g1; acc[1][2] += w1 * g2; acc[1][3] += w1 * g3;
      acc[2][0] += w2 * g0; acc[2][1] += w2 * g1; acc[2][2] += w2 * g2; acc[2][3] += w2 * g3;
      acc[3][0] += w3 * g0; acc[3][1] += w3 * g1; acc[3][2] += w3 * g2; acc[3][3] += w3 * g3;
    }
  }
  float* vb = V + ((size_t)b << 18);
#pragma unroll
  for (int a = 0; a < 4; ++a) {
    float4 vv = {acc[a][0], acc[a][1], acc[a][2], acc[a][3]};
    *reinterpret_cast<float4*>(vb + ((size_t)(o0 + oy + a) << 9) + i0 + ix) = vv;
  }
}

// ---------- kernel 4: att/tsq/tsum per (b,o)
__global__ __launch_bounds__(256) void k_red2(const float* __restrict__ V,
                                              const float* __restrict__ xsum,
                                              const float* __restrict__ Wp,
                                              const float* __restrict__ Wt,
                                              float* __restrict__ att,
                                              float* __restrict__ tsum,
                                              float* __restrict__ tsq) {
  int blk = blockIdx.x;
  int b = blk >> 4;
  int og = (blk & 15) << 4;
  int tid = threadIdx.x;
  int ol = tid >> 4, seg = tid & 15;
  int o = og + ol;
  const float* vg = V + ((size_t)b << 18) + ((size_t)o << 9) + seg * 32;
  const float* vt = V + ((size_t)b << 18) + ((size_t)(256 + o) << 9) + seg * 32;
  const float* wp = Wp + (size_t)o * 512 + seg * 32;
  const float* wt = Wt + (size_t)o * 512 + seg * 32;
  const float* xs = xsum + b * CIN + seg * 32;
  float sa = 0.f, sq = 0.f, sm = 0.f;
#pragma unroll
  for (int i = 0; i < 32; i += 4) {
    float4 a = *reinterpret_cast<const float4*>(vg + i);
    float4 p = *reinterpret_cast<const float4*>(wp + i);
    float4 c = *reinterpret_cast<const float4*>(vt + i);
    float4 t = *reinterpret_cast<const float4*>(wt + i);
    float4 s = *reinterpret_cast<const float4*>(xs + i);
    sa += a.x * p.x + a.y * p.y + a.z * p.z + a.w * p.w;
    sq += c.x * t.x + c.y * t.y + c.z * t.z + c.w * t.w;
    sm += t.x * s.x + t.y * s.y + t.z * s.z + t.w * s.w;
  }
#pragma unroll
  for (int m = 1; m < 16; m <<= 1) {
    sa += __shfl_xor(sa, m);
    sq += __shfl_xor(sq, m);
    sm += __shfl_xor(sm, m);
  }
  if (seg == 0) {
    att[b * PL + o] = sa;
    tsq[b * PL + o] = sq;
    tsum[b * PL + o] = sm;
  }
}

// ---------- kernel 5: graph math (one block, 1024 threads)
__global__ __launch_bounds__(1024) void k_graph(
    const float* __restrict__ att, const float* __restrict__ tsum, const float* __restrict__ tsq,
    const float* __restrict__ W_adj, const float* __restrict__ bnag, const float* __restrict__ bnab,
    const float* __restrict__ bnam, const float* __restrict__ bnav,
    const float* __restrict__ W_wg, const float* __restrict__ bwgg, const float* __restrict__ bwgb,
    const float* __restrict__ bwgm, const float* __restrict__ bwgv,
    const float* __restrict__ Wz, const float* __restrict__ gng, const float* __restrict__ gnb,
    float* __restrict__ sA, float* __restrict__ sB) {
  __shared__ float att_l[4 * 256];
  __shared__ float z_l[4 * 256];
  __shared__ float zv_l[4 * 256];
  int tid = threadIdx.x;
  att_l[tid] = att[tid];
  __syncthreads();
  int b = tid >> 8, r = tid & 255, i = r >> 3, k = r & 7;
  float z1 = 0.f;
#pragma unroll
  for (int m = 0; m < 32; ++m) z1 += W_adj[i * 32 + m] * att_l[b * 256 + k * 32 + m];
  float inv = rsqrtf(bnav[i] + EPSF);
  float z = (z1 - bnam[i]) * inv * bnag[i] + bnab[i];
  z = fmaxf(z, 0.f) + att_l[b * 256 + k * 32 + i];
  z_l[b * 256 + i * 8 + k] = z;
  __syncthreads();
  float z2 = 0.f;
#pragma unroll
  for (int e = 0; e < 8; ++e) z2 += W_wg[k * 8 + e] * z_l[b * 256 + i * 8 + e];
  float inv2 = rsqrtf(bwgv[k] + EPSF);
  z2 = (z2 - bwgm[k]) * inv2 * bwgg[k] + bwgb[k];
  zv_l[b * 256 + i * 8 + k] = fmaxf(z2, 0.f);
  __syncthreads();
  int g = r;
  float s = zv_l[b * 256 + g];
  float m1 = tsum[b * 256 + g] * (1.f / 16384.f);
  float m2 = tsq[b * 256 + g] * (1.f / 16384.f);
  float a0 = Wz[2 * g] * s, a1 = Wz[2 * g + 1] * s;
  float mu = 0.5f * (a0 + a1) * m1;
  float ey2 = 0.5f * (a0 * a0 + a1 * a1) * m2;
  float var = ey2 - mu * mu;
  float invg = rsqrtf(var + EPSF);
  int c = b * CIN + 2 * g;
  sA[c]     = a0 * invg * gng[2 * g];
  sA[c + 1] = a1 * invg * gng[2 * g + 1];
  sB[c]     = gnb[2 * g]     - mu * invg * gng[2 * g];
  sB[c + 1] = gnb[2 * g + 1] - mu * invg * gng[2 * g + 1];
}

// ---------- kernel 6: M[b][c][k] = fp16(sA[b,c]*Wt[c>>1][k] + (c==k))
__global__ __launch_bounds__(256) void k_M(const float* __restrict__ Wt,
                                           const float* __restrict__ sA,
                                           _Float16* __restrict__ M) {
  int idx = blockIdx.x * 256 + threadIdx.x;
  int k8 = idx & 63;
  int c = (idx >> 6) & 511;
  int b = idx >> 15;
  float s = sA[b * 512 + c];
  const float* wrow = Wt + ((size_t)(c >> 1) << 9) + k8 * 8;
  int kbase = k8 * 8;
  half8 h;
#pragma unroll
  for (int j = 0; j < 8; ++j) {
    float v = s * wrow[j] + ((kbase + j) == c ? 1.f : 0.f);
    h[j] = (_Float16)v;
  }
  *reinterpret_cast<half8*>(M + (((size_t)(b * 512 + c)) << 9) + kbase) = h;
}

// ---------- kernel 7: out = M_b . xT + sB — BK=64 (32 MFMA per barrier-pair).
__global__ __launch_bounds__(256, 4) void k_tout(const _Float16* __restrict__ xT,
                                                 const _Float16* __restrict__ M,
                                                 const float* __restrict__ sB,
                                                 float* __restrict__ out) {
  __shared__ _Float16 lA[128 * 64];   // 16KB
  __shared__ _Float16 lB[128 * 64];   // 16KB
  int wg = blockIdx.x;                 // 2048 blocks
  int id = (wg & 7) * 256 + (wg >> 3);
  int b = id >> 9;
  int rem = id & 511;
  int ct = rem >> 7;
  int ht = rem & 127;
  int tid = threadIdx.x;
  int wave = tid >> 6, lane = tid & 63, l15 = lane & 15, l4 = lane >> 4;
  int wr = wave >> 1, wc = wave & 1;
  const _Float16* Mb = M + ((size_t)b << 18);
  const _Float16* xTb = xT + (size_t)b * HW * CIN;

  int srow = lane >> 3;
  int sgran = (lane & 7) ^ (srow & 7);
  const _Float16* gA[4];
  const _Float16* gB[4];
#pragma unroll
  for (int i = 0; i < 4; ++i) {
    int row = i * 32 + wave * 8 + srow;
    gA[i] = Mb + ((size_t)(ct * 128 + row) << 9) + sgran * 8;
    gB[i] = xTb + ((size_t)(ht * 128 + row) << 9) + sgran * 8;
  }
  char* ldA = (char*)lA + wave * 1024;
  char* ldB = (char*)lB + wave * 1024;

  int adA[4][2], adB[4][2];
#pragma unroll
  for (int rf = 0; rf < 4; ++rf) {
    int r = wr * 64 + rf * 16 + l15;
#pragma unroll
    for (int ksub = 0; ksub < 2; ++ksub)
      adA[rf][ksub] = r * 128 + (((ksub * 4 + l4) ^ (r & 7)) << 4);
  }
#pragma unroll
  for (int cf = 0; cf < 4; ++cf) {
    int c = wc * 64 + cf * 16 + l15;
#pragma unroll
    for (int ksub = 0; ksub < 2; ++ksub)
      adB[cf][ksub] = c * 128 + (((ksub * 4 + l4) ^ (c & 7)) << 4);
  }

  f32x4 acc[4][4];
#pragma unroll
  for (int rf = 0; rf < 4; ++rf)
#pragma unroll
    for (int cf = 0; cf < 4; ++cf) acc[rf][cf] = f32x4{0.f, 0.f, 0.f, 0.f};

  for (int s = 0; s < 8; ++s) {
    int ko = s * 64;
#pragma unroll
    for (int i = 0; i < 4; ++i) {
      gload_lds16(gA[i] + ko, ldA + i * 4096);
      gload_lds16(gB[i] + ko, ldB + i * 4096);
    }
    __syncthreads();
#pragma unroll
    for (int ksub = 0; ksub < 2; ++ksub) {
      half8 af[4], bf[4];
#pragma unroll
      for (int rf = 0; rf < 4; ++rf)
        af[rf] = *reinterpret_cast<const half8*>((char*)lA + adA[rf][ksub]);
#pragma unroll
      for (int cf = 0; cf < 4; ++cf)
        bf[cf] = *reinterpret_cast<const half8*>((char*)lB + adB[cf][ksub]);
#pragma unroll
      for (int rf = 0; rf < 4; ++rf)
#pragma unroll
        for (int cf = 0; cf < 4; ++cf)
          acc[rf][cf] = __builtin_amdgcn_mfma_f32_16x16x32_f16(af[rf], bf[cf], acc[rf][cf], 0, 0, 0);
    }
    __syncthreads();
  }

  size_t outb = ((size_t)b * CIN) << 14;
#pragma unroll
  for (int rf = 0; rf < 4; ++rf) {
#pragma unroll
    for (int r = 0; r < 4; ++r) {
      int c = ct * 128 + wr * 64 + rf * 16 + l4 * 4 + r;
      float bb = sB[b * CIN + c];
      size_t off = outb + ((size_t)c << 14) + ht * 128 + wc * 64 + l15;
#pragma unroll
      for (int cf = 0; cf < 4; ++cf)
        out[off + cf * 16] = acc[rf][cf][r] + bb;
    }
  }
}

// ---------- launch
extern "C" void kernel_launch(void* const* d_in, const int* in_sizes, int n_in,
                              void* d_out, int out_size, void* d_ws, size_t ws_size,
                              hipStream_t stream) {
  const float* x    = (const float*)d_in[0];
  const float* Wt   = (const float*)d_in[1];
  const float* Wp   = (const float*)d_in[2];
  const float* Wg   = (const float*)d_in[3];
  const float* Wz   = (const float*)d_in[4];
  const float* Wadj = (const float*)d_in[5];
  const float* bnag = (const float*)d_in[6];
  const float* bnab = (const float*)d_in[7];
  const float* bnam = (const float*)d_in[8];
  const float* bnav = (const float*)d_in[9];
  const float* Wwg  = (const float*)d_in[10];
  const float* bwgg = (const float*)d_in[11];
  const float* bwgb = (const float*)d_in[12];
  const float* bwgm = (const float*)d_in[13];
  const float* bwgv = (const float*)d_in[14];
  const float* gng  = (const float*)d_in[15];
  const float* gnb  = (const float*)d_in[16];

  char* ws = (char*)d_ws;
  _Float16* xT = (_Float16*)(ws);                      // 67108864
  float* GH   = (float*)(ws + 67371008);               // 4194304 (reused for M after k_sym)
  float* C1   = (float*)(ws + 71565312);               // 4194304
  float* Gs   = (float*)(ws + 75759616);               // 4194304
  float* V    = (float*)(ws + 79953920);               // 4194304
  float* xsum = (float*)(ws + 84148224);               // 8192
  float* att  = (float*)(ws + 84156416);               // 4096
  float* tsum = (float*)(ws + 84160512);               // 4096
  float* tsq  = (float*)(ws + 84164608);               // 4096
  float* sA   = (float*)(ws + 84168704);               // 8192
  float* sB   = (float*)(ws + 84176896);               // 8192
  if (ws_size < (size_t)84185088) return;
  _Float16* M = (_Float16*)GH;                         // GH dead after k_sym

  _Float16* Xh = (_Float16*)((char*)d_out);            // 67108864
  _Float16* Xl = (_Float16*)((char*)d_out + 67108864); // 67108864
  float* out = (float*)d_out;

  hipMemsetAsync(GH, 0, 8388608, stream);              // GH + C1 (contiguous)
  k_conv<<<dim3(2048), dim3(256), 0, stream>>>(x, Xh, Xl, xsum);
  k_gx<<<dim3(9024), dim3(256), 0, stream>>>(Xh, Xl, GH, C1, xT);
  k_sym<<<dim3(8, 8, 4), dim3(256), 0, stream>>>(GH, C1, Gs);
  k_V<<<dim3(8, 8, 4), dim3(256), 0, stream>>>(Gs, Wg, Wt, V);
  k_red2<<<dim3(64), dim3(256), 0, stream>>>(V, xsum, Wp, Wt, att, tsum, tsq);
  k_graph<<<dim3(1), dim3(1024), 0, stream>>>(att, tsum, tsq, Wadj, bnag, bnab, bnam, bnav,
                                              Wwg, bwgg, bwgb, bwgm, bwgv, Wz, gng, gnb, sA, sB);
  k_M<<<dim3(512), dim3(256), 0, stream>>>(Wt, sA, M);
  k_tout<<<dim3(2048), dim3(256), 0, stream>>>(xT, M, sB, out);
}